// Round 12
// baseline (230.427 us; speedup 1.0000x reference)
//
#include <hip/hip_runtime.h>
#include <math.h>

#define NB 16
#define TT 800
#define FF 90
#define SS 128
#define LL 200
#define NEGV (-1e30f)

#define DNODES 16    // den nodes per utterance
#define DNDRX 50     // den frames per node (16*50 = 800)
#define QNODES 50    // num nodes per utterance
#define QDRX 16      // num frames per node
#define BROW 17      // band diagonals (QDRX+1)
#define NEGH (-60000.0f)
#define XSTR 68      // den X row stride in u32 words (pad kills bank alias)
#define LN2F 0.69314718055994531f
#define LOG2E 1.4426950408889634f

typedef __attribute__((ext_vector_type(8))) short short8;
typedef __attribute__((ext_vector_type(4))) float float4v;

static __device__ __forceinline__ unsigned short f2bf(float x) {
    union { float f; unsigned u; } v; v.f = x;
    unsigned r = (v.u + 0x7FFFu + ((v.u >> 16) & 1u)) >> 16;
    return (unsigned short)r;
}
static __device__ __forceinline__ unsigned pack2bf(float a, float b) {
    const unsigned ua = __float_as_uint(a), ub = __float_as_uint(b);
    return ((ua + 0x8000u) >> 16) | ((ub + 0x8000u) & 0xFFFF0000u);
}

// ======================= Kernel A ===========================================
// blocks [0, NB*DNODES): den node products, 8 waves (2/SIMD), validated
//   transpose-free MFMA chain.
// blocks [NB*DNODES, +NB*QNODES/2): TWO num band nodes per block (waves 0-3 /
//   4-7), band in registers + shfl_up, boundary lanes through LDS.
__global__ __launch_bounds__(512) void mmi_nodes(
    const float* __restrict__ x,
    const int*   __restrict__ sup,
    const float* __restrict__ trans,
    const int*   __restrict__ den_labels,
    const int*   __restrict__ num_labels,
    unsigned*    __restrict__ Pout,     // [NB*DNODES][8192] u32 (bf16 pairs)
    float*       __restrict__ scales,   // [NB*DNODES]
    _Float16*    __restrict__ Bd)       // [NB*QNODES][201][BROW]
{
    __shared__ __align__(16) unsigned char SMEM[60448];
    const int tid = threadIdx.x;

    if (blockIdx.x < NB * DNODES) {
        // ---------------- den node products ----------------
        unsigned* Xs  = (unsigned*)SMEM;                    // 34816 B
        float* ptab   = (float*)(SMEM + 34816);             // 50*128*4 = 25600 B
        float* sh_red = (float*)(SMEM + 60416);             // 8 floats

        const int bid = blockIdx.x;
        const int u  = bid / DNODES;
        const int nd = bid - u * DNODES;
        const int t0 = nd * DNDRX;
        const int nf = sup[u * 3 + 2];
        unsigned* Pg = Pout + (size_t)bid * 8192;

        if (t0 >= nf) {   // frozen node -> identity
            #pragma unroll
            for (int k2 = 0; k2 < 16; ++k2) {
                const int ww = tid + k2 * 512;
                const int row = ww >> 6, colw = ww & 63;
                unsigned val = 0;
                if (row == 2 * colw)     val |= 0x3F80u;
                if (row == 2 * colw + 1) val |= 0x3F800000u;
                Pg[ww] = val;
            }
            if (tid == 0) scales[bid] = 0.0f;
            return;
        }

        const int w = tid >> 6, l = tid & 63;
        const int m15 = l & 15, q = l >> 4;
        const int mB  = w & 1;    // 64-col half of X_new
        const int nB2 = w >> 1;   // 32-row block (0..3)

        // A = E^T fragments: afrag[mt][kc][j] = E[kc*32+q*8+j][mB*64+mt*16+m15]
        short8 afrag[4][4];
        #pragma unroll
        for (int mt = 0; mt < 4; ++mt) {
            const int colm = mB * 64 + mt * 16 + m15;
            #pragma unroll
            for (int kc = 0; kc < 4; ++kc) {
                short8 f;
                #pragma unroll
                for (int j = 0; j < 8; ++j)
                    f[j] = (short)f2bf(__expf(trans[(kc * 32 + q * 8 + j) * SS + colm]));
                afrag[mt][kc] = f;
            }
        }

        // emission table: ptab[t][d] = exp(x[u][t0+t][lab[d]])
        for (int idx = tid; idx < DNDRX * SS; idx += 512) {
            const int tt = idx >> 7, d = idx & 127;
            const int fr = min(t0 + tt, TT - 1);
            ptab[idx] = __expf(x[((size_t)u * TT + fr) * FF + den_labels[d]]);
        }
        __syncthreads();

        // X init = E * diag(p_0), row-major bf16 pairs
        #pragma unroll
        for (int k2 = 0; k2 < 16; ++k2) {
            const int ww = tid + k2 * 512;
            const int row = ww >> 6, colw = ww & 63;
            const float2 t2 = ((const float2*)trans)[ww];
            const float p0 = ptab[2 * colw], p1 = ptab[2 * colw + 1];
            Xs[row * XSTR + colw] = pack2bf(__expf(t2.x) * p0, __expf(t2.y) * p1);
        }
        if (tid < 8) sh_red[tid] = 1.0f;
        int eacc = 0;
        __syncthreads();

        const unsigned short* Xh = (const unsigned short*)Xs;
        const int kmax = min(DNDRX, nf - t0);

        for (int k = 1; k < kmax; ++k) {
            float mm = sh_red[0];
            #pragma unroll
            for (int i = 1; i < 8; ++i) mm = fmaxf(mm, sh_red[i]);
            const int e = (int)((__float_as_uint(mm) >> 23) & 255u);
            const float sc = __uint_as_float((unsigned)(254 - e) << 23);
            eacc += (e - 127);

            float4v acc[4][2];
            #pragma unroll
            for (int mt = 0; mt < 4; ++mt)
                #pragma unroll
                for (int nt = 0; nt < 2; ++nt) {
                    float4v z = {0.f, 0.f, 0.f, 0.f};
                    acc[mt][nt] = z;
                }
            #pragma unroll
            for (int kc = 0; kc < 4; ++kc)
                #pragma unroll
                for (int nt = 0; nt < 2; ++nt) {
                    const int row = nB2 * 32 + nt * 16 + m15;
                    const short8 bf = *(const short8*)(Xh + row * (2 * XSTR) +
                                                       kc * 32 + q * 8);
                    #pragma unroll
                    for (int mt = 0; mt < 4; ++mt)
                        acc[mt][nt] = __builtin_amdgcn_mfma_f32_16x16x32_bf16(
                            afrag[mt][kc], bf, acc[mt][nt], 0, 0, 0);
                }

            float vmax = 0.0f;
            #pragma unroll
            for (int mt = 0; mt < 4; ++mt) {
                const float4 pc = *(const float4*)(ptab + k * SS + mB * 64 +
                                                   mt * 16 + 4 * q);
                #pragma unroll
                for (int nt = 0; nt < 2; ++nt) {
                    acc[mt][nt][0] *= pc.x * sc;
                    acc[mt][nt][1] *= pc.y * sc;
                    acc[mt][nt][2] *= pc.z * sc;
                    acc[mt][nt][3] *= pc.w * sc;
                    vmax = fmaxf(vmax, fmaxf(fmaxf(acc[mt][nt][0], acc[mt][nt][1]),
                                             fmaxf(acc[mt][nt][2], acc[mt][nt][3])));
                }
            }
            #pragma unroll
            for (int off = 32; off >= 1; off >>= 1)
                vmax = fmaxf(vmax, __shfl_xor(vmax, off, 64));

            __syncthreads();   // all X reads retired; prev sh_red consumed
            if (l == 0) sh_red[w] = vmax;

            #pragma unroll
            for (int nt = 0; nt < 2; ++nt) {
                const int row = nB2 * 32 + nt * 16 + m15;
                #pragma unroll
                for (int mt = 0; mt < 4; ++mt) {
                    uint2 pk;
                    pk.x = pack2bf(acc[mt][nt][0], acc[mt][nt][1]);
                    pk.y = pack2bf(acc[mt][nt][2], acc[mt][nt][3]);
                    *(uint2*)(Xs + row * XSTR + mB * 32 + mt * 8 + 2 * q) = pk;
                }
            }
            __syncthreads();   // new X + maxes visible
        }

        #pragma unroll
        for (int k2 = 0; k2 < 16; ++k2) {
            const int ww = tid + k2 * 512;
            Pg[ww] = Xs[(ww >> 6) * XSTR + (ww & 63)];
        }
        if (tid == 0) scales[bid] = (float)eacc;
        return;
    }

    // ---------------- num band products: 2 nodes/block, register band -------
    {
        float* est = (float*)SMEM;                 // [2][16*200] = 25600 B
        float* bnd = (float*)(SMEM + 25600);       // [2 par][2 g][3][16] = 1536 B

        const int bid2 = blockIdx.x - NB * DNODES;
        const int g  = tid >> 8;       // node half 0/1
        const int r  = tid & 255;      // row index within half
        const int gw = r >> 6;         // wave within half (0..3)
        const int l  = tid & 63;
        const int slot = bid2 * 2 + g;             // 0..799
        const int u  = slot / QNODES;
        const int nd = slot - u * QNODES;
        const int t0 = nd * QDRX;
        const int nf = sup[u * 3 + 2];
        const int kmaxg = min(QDRX, max(nf - t0, 0));
        const int* nlu = num_labels + u * LL;
        float* eg = est + g * (QDRX * 200);

        for (int idx = r; idx < QDRX * 200; idx += 256) {
            const int tt = idx / 200, j = idx - tt * 200;
            const int fr = min(t0 + tt, TT - 1);
            eg[idx] = x[((size_t)u * TT + fr) * FF + nlu[j]] * LOG2E;
        }

        float dv[BROW];
        dv[0] = 0.0f;
        #pragma unroll
        for (int k = 1; k < BROW; ++k) dv[k] = NEGV;
        if (l == 63 && gw < 3) {   // init boundary into parity 1
            float4* bb = (float4*)(bnd + ((1 * 2 + g) * 3 + gw) * 16);
            bb[0] = make_float4(dv[0], dv[1], dv[2], dv[3]);
            bb[1] = make_float4(dv[4], dv[5], dv[6], dv[7]);
            bb[2] = make_float4(dv[8], dv[9], dv[10], dv[11]);
            bb[3] = make_float4(dv[12], dv[13], dv[14], dv[15]);
        }
        __syncthreads();

        for (int t = 0; t < QDRX; ++t) {
            const int par = t & 1;
            const bool act = (t < kmaxg);
            const bool upd = act && (r >= 1) && (r <= 200);
            float er = 0.0f;
            if (r >= 1 && r <= 200) er = eg[t * 200 + (r - 1)];

            float pv[16];
            #pragma unroll
            for (int k = 0; k < 16; ++k) pv[k] = __shfl_up(dv[k], 1, 64);
            if (l == 0 && gw > 0) {
                const float4* bb = (const float4*)(bnd +
                    (((par ^ 1) * 2 + g) * 3 + (gw - 1)) * 16);
                #pragma unroll
                for (int k = 0; k < 4; ++k) {
                    const float4 f4 = bb[k];
                    pv[4 * k + 0] = f4.x; pv[4 * k + 1] = f4.y;
                    pv[4 * k + 2] = f4.z; pv[4 * k + 3] = f4.w;
                }
            }

            float nv[BROW];
            nv[0] = er + dv[0];
            #pragma unroll
            for (int k = 1; k < BROW; ++k) {
                const float a = pv[k - 1], b = dv[k];
                const float mx = fmaxf(a, b);
                const float d = fminf(a, b) - mx;
                nv[k] = er + mx +
                    __builtin_amdgcn_logf(1.0f + __builtin_amdgcn_exp2f(d));
            }
            const bool zrow = act && (r == 0);
            #pragma unroll
            for (int k = 0; k < BROW; ++k)
                dv[k] = upd ? nv[k] : (zrow ? NEGV : dv[k]);

            if (l == 63 && gw < 3) {
                float4* bb = (float4*)(bnd + ((par * 2 + g) * 3 + gw) * 16);
                bb[0] = make_float4(dv[0], dv[1], dv[2], dv[3]);
                bb[1] = make_float4(dv[4], dv[5], dv[6], dv[7]);
                bb[2] = make_float4(dv[8], dv[9], dv[10], dv[11]);
                bb[3] = make_float4(dv[12], dv[13], dv[14], dv[15]);
            }
            __syncthreads();
        }

        _Float16* Bg = Bd + (size_t)slot * 201 * BROW;
        if (r < 201) {
            #pragma unroll
            for (int k = 0; k < BROW; ++k)
                Bg[r * BROW + k] = (_Float16)fmaxf(dv[k], NEGH);
        }
    }
}

// ======================= Kernel B: chains (validated round 11) ===============
__global__ __launch_bounds__(256) void mmi_chain(
    const unsigned short* __restrict__ Pmat,   // [16][DNODES][128*128] bf16
    const _Float16* __restrict__ Bd,           // [16][QNODES][201][BROW]
    const float* __restrict__ scales,          // [16*DNODES]
    const int* __restrict__ num_lens,
    float* __restrict__ dsc)                   // [0..15] den, [16..31] num
{
    __shared__ float sh_v[SS];
    __shared__ float sh_part[8 * SS];
    __shared__ float sh_red[2];
    __shared__ float ab[2][224];

    const int tid = threadIdx.x;

    if (blockIdx.x < NB) {
        const int u = blockIdx.x;
        const int gg = tid & 31, c = tid >> 5;
        const unsigned short* Pu = Pmat + (size_t)u * DNODES * 16384;

        if (tid < SS) sh_v[tid] = (tid == 0) ? 1.0f : 0.0f;
        int   e2acc = 0;
        float sscal = 0.0f;

        uint2 curm[16], nxt[16];
        #pragma unroll
        for (int j = 0; j < 16; ++j)
            curm[j] = *(const uint2*)(Pu + (16 * c + j) * SS + 4 * gg);
        __syncthreads();

        for (int i = 0; i < DNODES; ++i) {
            if (i + 1 < DNODES) {
                const unsigned short* Pn = Pu + (size_t)(i + 1) * 16384;
                #pragma unroll
                for (int j = 0; j < 16; ++j)
                    nxt[j] = *(const uint2*)(Pn + (16 * c + j) * SS + 4 * gg);
            }
            sscal += scales[u * DNODES + i];

            const float4* av = (const float4*)(sh_v + 16 * c);
            float4 aa[4] = {av[0], av[1], av[2], av[3]};
            const float* as = (const float*)aa;
            float4 acc = make_float4(0.f, 0.f, 0.f, 0.f);
            #pragma unroll
            for (int j = 0; j < 16; ++j) {
                const float e0 = __uint_as_float(curm[j].x << 16);
                const float e1 = __uint_as_float(curm[j].x & 0xFFFF0000u);
                const float e2 = __uint_as_float(curm[j].y << 16);
                const float e3 = __uint_as_float(curm[j].y & 0xFFFF0000u);
                acc.x = fmaf(as[j], e0, acc.x);
                acc.y = fmaf(as[j], e1, acc.y);
                acc.z = fmaf(as[j], e2, acc.z);
                acc.w = fmaf(as[j], e3, acc.w);
            }
            *(float4*)(sh_part + c * SS + 4 * gg) = acc;
            __syncthreads();

            float v = 0.0f;
            if (tid < SS) {
                float y = 0.0f;
                #pragma unroll
                for (int cc = 0; cc < 8; ++cc) y += sh_part[cc * SS + tid];
                v = y;
                float m = v;
                #pragma unroll
                for (int off = 32; off >= 1; off >>= 1)
                    m = fmaxf(m, __shfl_xor(m, off, 64));
                if ((tid & 63) == 0) sh_red[tid >> 6] = m;
            }
            __syncthreads();
            if (tid < SS) {
                const float mm = fmaxf(fmaxf(sh_red[0], sh_red[1]), 1e-37f);
                const int e = (int)((__float_as_uint(mm) >> 23) & 255u);
                const float inv = __uint_as_float((unsigned)(254 - e) << 23);
                e2acc += (e - 127);
                sh_v[tid] = v * inv;
            }
            #pragma unroll
            for (int j = 0; j < 16; ++j) curm[j] = nxt[j];
            __syncthreads();
        }

        if (tid < SS) {
            float s = sh_v[tid];
            #pragma unroll
            for (int off = 32; off >= 1; off >>= 1)
                s += __shfl_xor(s, off, 64);
            if ((tid & 63) == 0) sh_red[tid >> 6] = s;
        }
        __syncthreads();
        if (tid == 0)
            dsc[u] = LN2F * ((float)e2acc + sscal) + __logf(sh_red[0] + sh_red[1]);
    } else {
        const int u = blockIdx.x - NB;
        const _Float16* Bu = Bd + (size_t)u * QNODES * 201 * BROW;
        const int r = tid;

        if (r < 224) { ab[0][r] = NEGV; ab[1][r] = NEGV; }
        float dv[BROW];
        if (r < 201) {
            #pragma unroll
            for (int k = 0; k < BROW; ++k) dv[k] = (float)Bu[r * BROW + k];
        }
        __syncthreads();
        if (r == 0) ab[0][16] = 0.0f;
        __syncthreads();

        int cur = 0;
        for (int nd = 0; nd < QNODES; ++nd) {
            _Float16 nx[BROW];
            if (nd + 1 < QNODES && r < 201) {
                const _Float16* src = Bu + ((size_t)(nd + 1) * 201 + r) * BROW;
                #pragma unroll
                for (int k = 0; k < BROW; ++k) nx[k] = src[k];
            }
            float anew = NEGV;
            if (r < 201) {
                float tr[BROW];
                #pragma unroll
                for (int k = 0; k < BROW; ++k)
                    tr[k] = dv[k] + ab[cur][16 + r - k];
                float m = tr[0];
                #pragma unroll
                for (int k = 1; k < BROW; ++k) m = fmaxf(m, tr[k]);
                float s = 0.0f;
                #pragma unroll
                for (int k = 0; k < BROW; ++k)
                    s += __builtin_amdgcn_exp2f(tr[k] - m);
                anew = m + __builtin_amdgcn_logf(s);
            }
            if (r < 201) ab[cur ^ 1][16 + r] = anew;
            cur ^= 1;
            __syncthreads();
            if (r < 201) {
                #pragma unroll
                for (int k = 0; k < BROW; ++k) dv[k] = (float)nx[k];
            }
        }
        if (r == 0) dsc[NB + u] = ab[cur][16 + num_lens[u]] * LN2F;
    }
}

// ======================= Finalize ============================================
__global__ void mmi_finalize(const float* __restrict__ sc,
                             const int* __restrict__ sup,
                             float* __restrict__ out)
{
    const int tid = threadIdx.x;
    float tot_score = 0.0f, tot_frames = 0.0f, all_frames = 0.0f;
    if (tid < NB) {
        const float tot = sc[NB + tid] - sc[tid];
        const int nf = sup[tid * 3 + 2];
        const bool fin = isfinite(tot) && (tot > 0.5f * NEGV);
        tot_score  = fin ? tot : 0.0f;
        tot_frames = fin ? (float)nf : 0.0f;
        all_frames = (float)nf;
    }
    #pragma unroll
    for (int off = 32; off >= 1; off >>= 1) {
        tot_score  += __shfl_xor(tot_score, off, 64);
        tot_frames += __shfl_xor(tot_frames, off, 64);
        all_frames += __shfl_xor(all_frames, off, 64);
    }
    if (tid == 0) {
        out[0] = tot_score;
        out[1] = tot_frames;
        out[2] = all_frames;
    }
}

// ======================= Fallback (validated round-4 kernel) =================
#define XBF (16 * FF)
__global__ __launch_bounds__(256) void mmi_forward_fb(
    const float* __restrict__ x, const int* __restrict__ sup,
    const float* __restrict__ trans, const int* __restrict__ den_labels,
    const int* __restrict__ num_labels, const int* __restrict__ num_lens,
    float* __restrict__ ws)
{
    const int tid = threadIdx.x;
    if (blockIdx.x < NB) {
        __shared__ float sh_v[SS];
        __shared__ float sh_part[8 * SS];
        __shared__ float sh_red[4];
        __shared__ __align__(16) float xbuf[2][XBF];
        const int n = blockIdx.x, nf = sup[n * 3 + 2];
        const int g = tid & 31, c = tid >> 5;
        float4 e[16];
        #pragma unroll
        for (int j = 0; j < 16; ++j) {
            const float4 t4 = *(const float4*)(trans + (size_t)(16 * c + j) * SS + 4 * g);
            e[j] = make_float4(__expf(t4.x), __expf(t4.y), __expf(t4.z), __expf(t4.w));
        }
        const int lab = (tid < SS) ? den_labels[tid & (SS - 1)] : 0;
        const float* xb = x + (size_t)n * TT * FF;
        {
            const float4* s0 = (const float4*)xb;
            float4 p0 = s0[tid]; float4 p1; if (tid < 104) p1 = s0[256 + tid];
            float4* d0 = (float4*)xbuf[0];
            d0[tid] = p0; if (tid < 104) d0[256 + tid] = p1;
        }
        if (tid < SS) sh_v[tid] = (tid == 0) ? 1.0f : 0.0f;
        float logM = 0.0f, v = 0.0f, pe = 0.0f;
        float4 pf0, pf1;
        __syncthreads();
        for (int t = 0; t < nf; ++t) {
            const int b = t >> 4;
            if (tid < SS) pe = __expf(xbuf[b & 1][(t & 15) * FF + lab]);
            float4 aa[4];
            { const float4* av = (const float4*)(sh_v + 16 * c);
              aa[0] = av[0]; aa[1] = av[1]; aa[2] = av[2]; aa[3] = av[3]; }
            const float* as = (const float*)aa;
            float4 acc = make_float4(0.f, 0.f, 0.f, 0.f);
            #pragma unroll
            for (int j = 0; j < 16; ++j) {
                acc.x = fmaf(as[j], e[j].x, acc.x); acc.y = fmaf(as[j], e[j].y, acc.y);
                acc.z = fmaf(as[j], e[j].z, acc.z); acc.w = fmaf(as[j], e[j].w, acc.w);
            }
            *(float4*)(sh_part + c * SS + 4 * g) = acc;
            if ((t & 15) == 8) {
                const int tn = (b + 1) * 16;
                if (tn < nf) {
                    const float4* s = (const float4*)(xb + (size_t)tn * FF);
                    pf0 = s[tid]; if (tid < 104) pf1 = s[256 + tid];
                }
            }
            __syncthreads();
            const bool rs = ((t & 15) == 15);
            if (tid < SS) {
                float y = 0.0f;
                #pragma unroll
                for (int cc = 0; cc < 8; ++cc) y += sh_part[cc * SS + tid];
                v = y * pe;
                if (rs) {
                    float m = v;
                    #pragma unroll
                    for (int off = 32; off >= 1; off >>= 1)
                        m = fmaxf(m, __shfl_xor(m, off, 64));
                    if ((tid & 63) == 0) sh_red[tid >> 6] = m;
                }
            }
            if (rs) {
                const int tn = (b + 1) * 16;
                if (tn < nf) {
                    float4* dst = (float4*)xbuf[(b + 1) & 1];
                    dst[tid] = pf0; if (tid < 104) dst[256 + tid] = pf1;
                }
                __syncthreads();
                if (tid < SS) {
                    float mm = fmaxf(fmaxf(sh_red[0], sh_red[1]), 1e-37f);
                    v *= (1.0f / mm); logM += __logf(mm);
                }
            }
            if (tid < SS) sh_v[tid] = v;
            __syncthreads();
        }
        if (tid < SS) {
            float ssum = v;
            #pragma unroll
            for (int off = 32; off >= 1; off >>= 1) ssum += __shfl_xor(ssum, off, 64);
            if ((tid & 63) == 0) sh_red[2 + (tid >> 6)] = ssum;
        }
        __syncthreads();
        if (tid == 0) ws[n] = logM + __logf(sh_red[2] + sh_red[3]);
    } else {
        const int w = tid >> 6, l = tid & 63;
        const int n = (blockIdx.x - NB) * 4 + w;
        const int nf = sup[n * 3 + 2];
        const float* xb = x + (size_t)n * TT * FF;
        const int* nl = num_labels + n * LL;
        int li[4];
        #pragma unroll
        for (int k = 0; k < 4; ++k) li[k] = nl[min(4 * l + k, LL - 1)];
        float a4[4] = {NEGV, NEGV, NEGV, NEGV};
        float ea[4], eb[4];
        #pragma unroll
        for (int k = 0; k < 4; ++k) ea[k] = xb[li[k]];
        { const float* xr = xb + (size_t)min(1, nf - 1) * FF;
          #pragma unroll
          for (int k = 0; k < 4; ++k) eb[k] = xr[li[k]]; }
        auto step = [&](float (&ee)[4], int t) {
            float left = __shfl_up(a4[3], 1, 64);
            if (l == 0) left = (t == 0) ? 0.0f : NEGV;
            float prev = left;
            #pragma unroll
            for (int k = 0; k < 4; ++k) {
                const float a = a4[k], b = prev;
                const float mx = fmaxf(a, b), mn = fminf(a, b);
                const float nv = mx + __logf(1.0f + __expf(mn - mx)) + ee[k];
                prev = a4[k]; a4[k] = nv;
            }
            const int t2 = min(t + 2, nf - 1);
            const float* xr = xb + (size_t)t2 * FF;
            #pragma unroll
            for (int k = 0; k < 4; ++k) ee[k] = xr[li[k]];
        };
        int t = 0;
        while (t < nf) { step(ea, t); ++t; if (t >= nf) break; step(eb, t); ++t; }
        const int idx = num_lens[n] - 1;
        if ((idx >> 2) == l) {
            const int kk = idx & 3;
            float vv = (kk == 0) ? a4[0] : (kk == 1) ? a4[1] : (kk == 2) ? a4[2] : a4[3];
            ws[NB + n] = vv;
        }
    }
}

extern "C" void kernel_launch(void* const* d_in, const int* in_sizes, int n_in,
                              void* d_out, int out_size, void* d_ws, size_t ws_size,
                              hipStream_t stream) {
    const float* x          = (const float*)d_in[0];
    const int*   sup        = (const int*)d_in[1];
    const float* trans      = (const float*)d_in[2];
    const int*   den_labels = (const int*)d_in[3];
    const int*   num_labels = (const int*)d_in[4];
    const int*   num_lens   = (const int*)d_in[5];
    float* out = (float*)d_out;

    const size_t PBYTES = (size_t)NB * DNODES * 32768;              // 8,388,608
    const size_t BBYTES = (size_t)NB * QNODES * 201 * BROW * 2;     // 5,467,200
    const size_t SOFF   = PBYTES + BBYTES;
    const size_t NEEDED = SOFF + (NB * DNODES + 64) * sizeof(float);

    if (ws_size >= NEEDED) {
        unsigned*  Pout   = (unsigned*)d_ws;
        _Float16*  Bd     = (_Float16*)((char*)d_ws + PBYTES);
        float*     scales = (float*)((char*)d_ws + SOFF);
        float*     scores = scales + NB * DNODES;   // [0..15] den, [16..31] num
        mmi_nodes<<<dim3(NB * DNODES + NB * QNODES / 2), dim3(512), 0, stream>>>(
            x, sup, trans, den_labels, num_labels, Pout, scales, Bd);
        mmi_chain<<<dim3(2 * NB), dim3(256), 0, stream>>>(
            (const unsigned short*)d_ws, Bd, scales, num_lens, scores);
        mmi_finalize<<<dim3(1), dim3(64), 0, stream>>>(scores, sup, out);
    } else {
        float* ws = (float*)d_ws;
        mmi_forward_fb<<<dim3(20), dim3(256), 0, stream>>>(
            x, sup, trans, den_labels, num_labels, num_lens, ws);
        mmi_finalize<<<dim3(1), dim3(64), 0, stream>>>(ws, sup, out);
    }
}

// Round 14
// 213.208 us; speedup vs baseline: 1.0808x; 1.0808x over previous
//
#include <hip/hip_runtime.h>
#include <math.h>

#define NB 16
#define TT 800
#define FF 90
#define SS 128
#define LL 200
#define NEGV (-1e30f)

#define DNODES 16    // den nodes per utterance
#define DNDRX 50     // den frames per node (16*50 = 800)
#define QNODES 32    // num nodes per utterance
#define QDRX 25      // num frames per node
#define BROW 26      // band diagonals (QDRX+1)
#define NEGH (-60000.0f)
#define XSTR 68      // den X row stride in u32 words (pad kills bank alias)
#define LN2F 0.69314718055994531f
#define LOG2E 1.4426950408889634f

typedef __attribute__((ext_vector_type(8))) short short8;
typedef __attribute__((ext_vector_type(4))) float float4v;

static __device__ __forceinline__ unsigned short f2bf(float x) {
    union { float f; unsigned u; } v; v.f = x;
    unsigned r = (v.u + 0x7FFFu + ((v.u >> 16) & 1u)) >> 16;
    return (unsigned short)r;
}
// truncating bf16 pair pack: 2-3 VALU ops, values are non-negative
static __device__ __forceinline__ unsigned pack2bf_t(float a, float b) {
    return (__float_as_uint(a) >> 16) | (__float_as_uint(b) & 0xFFFF0000u);
}

// ======================= Kernel A ===========================================
// 512 blocks, all co-resident (one generation, 2 blocks/CU):
//   even blockIdx -> den node product (transpose-free MFMA, validated r8-r12)
//   odd  blockIdx -> TWO num band nodes (QDRX=25 frames, register band,
//                    descending in-place update)
__global__ __launch_bounds__(512, 4) void mmi_nodes(
    const float* __restrict__ x,
    const int*   __restrict__ sup,
    const float* __restrict__ trans,
    const int*   __restrict__ den_labels,
    const int*   __restrict__ num_labels,
    unsigned*    __restrict__ Pout,     // [NB*DNODES][8192] u32 (bf16 pairs)
    float*       __restrict__ scales,   // [NB*DNODES]
    _Float16*    __restrict__ Bd)       // [NB*QNODES][201][BROW]
{
    __shared__ __align__(16) unsigned char SMEM[60448];
    const int tid = threadIdx.x;
    const int half = blockIdx.x >> 1;

    if ((blockIdx.x & 1) == 0) {
        // ---------------- den node product ----------------
        unsigned* Xs  = (unsigned*)SMEM;                    // 34816 B
        float* ptab   = (float*)(SMEM + 34816);             // 50*128*4 = 25600 B
        float* sh_red = (float*)(SMEM + 60416);             // 8 floats

        const int bid = half;
        const int u  = bid / DNODES;
        const int nd = bid - u * DNODES;
        const int t0 = nd * DNDRX;
        const int nf = sup[u * 3 + 2];
        unsigned* Pg = Pout + (size_t)bid * 8192;

        if (t0 >= nf) {   // frozen node -> identity
            #pragma unroll
            for (int k2 = 0; k2 < 16; ++k2) {
                const int ww = tid + k2 * 512;
                const int row = ww >> 6, colw = ww & 63;
                unsigned val = 0;
                if (row == 2 * colw)     val |= 0x3F80u;
                if (row == 2 * colw + 1) val |= 0x3F800000u;
                Pg[ww] = val;
            }
            if (tid == 0) scales[bid] = 0.0f;
            return;
        }

        const int w = tid >> 6, l = tid & 63;
        const int m15 = l & 15, q = l >> 4;
        const int mB  = w & 1;    // 64-col half of X_new
        const int nB2 = w >> 1;   // 32-row block (0..3)

        // A = E^T fragments
        short8 afrag[4][4];
        #pragma unroll
        for (int mt = 0; mt < 4; ++mt) {
            const int colm = mB * 64 + mt * 16 + m15;
            #pragma unroll
            for (int kc = 0; kc < 4; ++kc) {
                short8 f;
                #pragma unroll
                for (int j = 0; j < 8; ++j)
                    f[j] = (short)f2bf(__expf(trans[(kc * 32 + q * 8 + j) * SS + colm]));
                afrag[mt][kc] = f;
            }
        }

        for (int idx = tid; idx < DNDRX * SS; idx += 512) {
            const int tt = idx >> 7, d = idx & 127;
            const int fr = min(t0 + tt, TT - 1);
            ptab[idx] = __expf(x[((size_t)u * TT + fr) * FF + den_labels[d]]);
        }
        __syncthreads();

        #pragma unroll
        for (int k2 = 0; k2 < 16; ++k2) {
            const int ww = tid + k2 * 512;
            const int row = ww >> 6, colw = ww & 63;
            const float2 t2 = ((const float2*)trans)[ww];
            const float p0 = ptab[2 * colw], p1 = ptab[2 * colw + 1];
            Xs[row * XSTR + colw] = pack2bf_t(__expf(t2.x) * p0, __expf(t2.y) * p1);
        }
        if (tid < 8) sh_red[tid] = 1.0f;
        int eacc = 0;
        __syncthreads();

        const unsigned short* Xh = (const unsigned short*)Xs;
        const int kmax = min(DNDRX, nf - t0);

        for (int k = 1; k < kmax; ++k) {
            // pow2 renorm applied every 4th step (bf16 range covers the drift)
            float sc = 1.0f;
            if ((k & 3) == 0) {
                float mm = sh_red[0];
                #pragma unroll
                for (int i = 1; i < 8; ++i) mm = fmaxf(mm, sh_red[i]);
                mm = fmaxf(mm, 1e-37f);
                const int e = (int)((__float_as_uint(mm) >> 23) & 255u);
                sc = __uint_as_float((unsigned)(254 - e) << 23);
                eacc += (e - 127);
            }

            float4v acc[4][2];
            #pragma unroll
            for (int mt = 0; mt < 4; ++mt)
                #pragma unroll
                for (int nt = 0; nt < 2; ++nt) {
                    float4v z = {0.f, 0.f, 0.f, 0.f};
                    acc[mt][nt] = z;
                }
            #pragma unroll
            for (int kc = 0; kc < 4; ++kc)
                #pragma unroll
                for (int nt = 0; nt < 2; ++nt) {
                    const int row = nB2 * 32 + nt * 16 + m15;
                    const short8 bf = *(const short8*)(Xh + row * (2 * XSTR) +
                                                       kc * 32 + q * 8);
                    #pragma unroll
                    for (int mt = 0; mt < 4; ++mt)
                        acc[mt][nt] = __builtin_amdgcn_mfma_f32_16x16x32_bf16(
                            afrag[mt][kc], bf, acc[mt][nt], 0, 0, 0);
                }

            // emission (pre-scaled by sc) + optional vmax for next renorm
            const bool dmax = ((k & 3) == 3);
            float vmax = 0.0f;
            #pragma unroll
            for (int mt = 0; mt < 4; ++mt) {
                float4 pc = *(const float4*)(ptab + k * SS + mB * 64 +
                                             mt * 16 + 4 * q);
                pc.x *= sc; pc.y *= sc; pc.z *= sc; pc.w *= sc;
                #pragma unroll
                for (int nt = 0; nt < 2; ++nt) {
                    acc[mt][nt][0] *= pc.x;
                    acc[mt][nt][1] *= pc.y;
                    acc[mt][nt][2] *= pc.z;
                    acc[mt][nt][3] *= pc.w;
                    if (dmax)
                        vmax = fmaxf(vmax,
                            fmaxf(fmaxf(acc[mt][nt][0], acc[mt][nt][1]),
                                  fmaxf(acc[mt][nt][2], acc[mt][nt][3])));
                }
            }
            if (dmax) {
                #pragma unroll
                for (int off = 32; off >= 1; off >>= 1)
                    vmax = fmaxf(vmax, __shfl_xor(vmax, off, 64));
            }

            __syncthreads();   // all X reads retired; prev sh_red consumed
            if (dmax && l == 0) sh_red[w] = vmax;

            #pragma unroll
            for (int nt = 0; nt < 2; ++nt) {
                const int row = nB2 * 32 + nt * 16 + m15;
                #pragma unroll
                for (int mt = 0; mt < 4; ++mt) {
                    uint2 pk;
                    pk.x = pack2bf_t(acc[mt][nt][0], acc[mt][nt][1]);
                    pk.y = pack2bf_t(acc[mt][nt][2], acc[mt][nt][3]);
                    *(uint2*)(Xs + row * XSTR + mB * 32 + mt * 8 + 2 * q) = pk;
                }
            }
            __syncthreads();   // new X + maxes visible
        }

        #pragma unroll
        for (int k2 = 0; k2 < 16; ++k2) {
            const int ww = tid + k2 * 512;
            Pg[ww] = Xs[(ww >> 6) * XSTR + (ww & 63)];
        }
        if (tid == 0) scales[bid] = (float)eacc;
        return;
    }

    // ---------------- num band products: 2 nodes/block ----------------
    {
        float* est = (float*)SMEM;                 // [2][25*200] f32 = 40000 B
        float* bnd = (float*)(SMEM + 40000);       // [2 par][2 g][3][28] = 2688 B

        const int g  = tid >> 8;       // node half 0/1
        const int r  = tid & 255;      // row index within half
        const int gw = r >> 6;         // wave within half (0..3)
        const int l  = tid & 63;
        const int slot = half * 2 + g;             // 0..511
        const int u  = slot / QNODES;
        const int nd = slot - u * QNODES;
        const int t0 = nd * QDRX;
        const int nf = sup[u * 3 + 2];
        const int kmaxg = min(QDRX, max(nf - t0, 0));
        const int* nlu = num_labels + u * LL;
        float* eg = est + g * (QDRX * 200);

        for (int idx = r; idx < QDRX * 200; idx += 256) {
            const int tt = idx / 200, j = idx - tt * 200;
            const int fr = min(t0 + tt, TT - 1);
            eg[idx] = x[((size_t)u * TT + fr) * FF + nlu[j]] * LOG2E;
        }

        float dv[BROW];
        dv[0] = 0.0f;
        #pragma unroll
        for (int k = 1; k < BROW; ++k) dv[k] = NEGV;
        if (l == 63 && gw < 3) {   // init boundary into parity 1
            float4* bb = (float4*)(bnd + ((1 * 2 + g) * 3 + gw) * 28);
            #pragma unroll
            for (int i = 0; i < 7; ++i) {
                float4 f4;
                f4.x = dv[min(4 * i + 0, BROW - 1)];
                f4.y = dv[min(4 * i + 1, BROW - 1)];
                f4.z = dv[min(4 * i + 2, BROW - 1)];
                f4.w = dv[min(4 * i + 3, BROW - 1)];
                bb[i] = f4;
            }
        }
        __syncthreads();

        for (int t = 0; t < QDRX; ++t) {
            const int par = t & 1;
            const bool act = (t < kmaxg);
            const bool upd = act && (r >= 1) && (r <= 200);
            const bool zrow = act && (r == 0);
            float er = 0.0f;
            if (r >= 1 && r <= 200) er = eg[t * 200 + (r - 1)];

            // boundary values of previous wave (lane 0 uses them)
            float4 bb7[7];
            if (gw > 0) {
                const float4* bb = (const float4*)(bnd +
                    (((par ^ 1) * 2 + g) * 3 + (gw - 1)) * 28);
                #pragma unroll
                for (int i = 0; i < 7; ++i) bb7[i] = bb[i];
            }

            // descending in-place band update: dv[k] <- er + lse(pv[k-1], dv[k])
            #pragma unroll
            for (int k = BROW - 1; k >= 1; --k) {
                float pvk = __shfl_up(dv[k - 1], 1, 64);
                if (l == 0 && gw > 0) {
                    const float4 f4 = bb7[(k - 1) >> 2];
                    const int c = (k - 1) & 3;
                    pvk = (c == 0) ? f4.x : (c == 1) ? f4.y : (c == 2) ? f4.z : f4.w;
                }
                const float a = pvk, b = dv[k];
                const float mx = fmaxf(a, b);
                const float d = fminf(a, b) - mx;
                const float nv = er + mx +
                    __builtin_amdgcn_logf(1.0f + __builtin_amdgcn_exp2f(d));
                dv[k] = upd ? nv : dv[k];
            }
            dv[0] = upd ? (er + dv[0]) : dv[0];
            if (zrow) {
                #pragma unroll
                for (int k = 0; k < BROW; ++k) dv[k] = NEGV;
            }

            if (l == 63 && gw < 3) {
                float4* bb = (float4*)(bnd + ((par * 2 + g) * 3 + gw) * 28);
                #pragma unroll
                for (int i = 0; i < 7; ++i) {
                    float4 f4;
                    f4.x = dv[min(4 * i + 0, BROW - 1)];
                    f4.y = dv[min(4 * i + 1, BROW - 1)];
                    f4.z = dv[min(4 * i + 2, BROW - 1)];
                    f4.w = dv[min(4 * i + 3, BROW - 1)];
                    bb[i] = f4;
                }
            }
            __syncthreads();
        }

        // write band rows as fp16
        _Float16* Bg = Bd + (size_t)slot * 201 * BROW;
        if (r < 201) {
            #pragma unroll
            for (int k = 0; k < BROW; ++k)
                Bg[r * BROW + k] = (_Float16)fmaxf(dv[k], NEGH);
        }
    }
}

// ======================= Kernel B: chains ====================================
__global__ __launch_bounds__(256) void mmi_chain(
    const unsigned short* __restrict__ Pmat,   // [16][DNODES][128*128] bf16
    const _Float16* __restrict__ Bd,           // [16][QNODES][201][BROW]
    const float* __restrict__ scales,          // [16*DNODES]
    const int* __restrict__ num_lens,
    float* __restrict__ dsc)                   // [0..15] den, [16..31] num
{
    __shared__ float sh_v[SS];
    __shared__ float sh_part[8 * SS];
    __shared__ float sh_red[2];
    __shared__ float ab[2][232];

    const int tid = threadIdx.x;

    if (blockIdx.x < NB) {
        const int u = blockIdx.x;
        const int gg = tid & 31, c = tid >> 5;
        const unsigned short* Pu = Pmat + (size_t)u * DNODES * 16384;

        if (tid < SS) sh_v[tid] = (tid == 0) ? 1.0f : 0.0f;
        int   e2acc = 0;
        float sscal = 0.0f;

        uint2 curm[16], nxt[16];
        #pragma unroll
        for (int j = 0; j < 16; ++j)
            curm[j] = *(const uint2*)(Pu + (16 * c + j) * SS + 4 * gg);
        __syncthreads();

        for (int i = 0; i < DNODES; ++i) {
            if (i + 1 < DNODES) {
                const unsigned short* Pn = Pu + (size_t)(i + 1) * 16384;
                #pragma unroll
                for (int j = 0; j < 16; ++j)
                    nxt[j] = *(const uint2*)(Pn + (16 * c + j) * SS + 4 * gg);
            }
            sscal += scales[u * DNODES + i];

            const float4* av = (const float4*)(sh_v + 16 * c);
            float4 aa[4] = {av[0], av[1], av[2], av[3]};
            const float* as = (const float*)aa;
            float4 acc = make_float4(0.f, 0.f, 0.f, 0.f);
            #pragma unroll
            for (int j = 0; j < 16; ++j) {
                const float e0 = __uint_as_float(curm[j].x << 16);
                const float e1 = __uint_as_float(curm[j].x & 0xFFFF0000u);
                const float e2 = __uint_as_float(curm[j].y << 16);
                const float e3 = __uint_as_float(curm[j].y & 0xFFFF0000u);
                acc.x = fmaf(as[j], e0, acc.x);
                acc.y = fmaf(as[j], e1, acc.y);
                acc.z = fmaf(as[j], e2, acc.z);
                acc.w = fmaf(as[j], e3, acc.w);
            }
            *(float4*)(sh_part + c * SS + 4 * gg) = acc;
            __syncthreads();

            float v = 0.0f;
            if (tid < SS) {
                float y = 0.0f;
                #pragma unroll
                for (int cc = 0; cc < 8; ++cc) y += sh_part[cc * SS + tid];
                v = y;
                float m = v;
                #pragma unroll
                for (int off = 32; off >= 1; off >>= 1)
                    m = fmaxf(m, __shfl_xor(m, off, 64));
                if ((tid & 63) == 0) sh_red[tid >> 6] = m;
            }
            __syncthreads();
            if (tid < SS) {
                const float mm = fmaxf(fmaxf(sh_red[0], sh_red[1]), 1e-37f);
                const int e = (int)((__float_as_uint(mm) >> 23) & 255u);
                const float inv = __uint_as_float((unsigned)(254 - e) << 23);
                e2acc += (e - 127);
                sh_v[tid] = v * inv;
            }
            #pragma unroll
            for (int j = 0; j < 16; ++j) curm[j] = nxt[j];
            __syncthreads();
        }

        if (tid < SS) {
            float s = sh_v[tid];
            #pragma unroll
            for (int off = 32; off >= 1; off >>= 1)
                s += __shfl_xor(s, off, 64);
            if ((tid & 63) == 0) sh_red[tid >> 6] = s;
        }
        __syncthreads();
        if (tid == 0)
            dsc[u] = LN2F * ((float)e2acc + sscal) + __logf(sh_red[0] + sh_red[1]);
    } else {
        // ---------------- num chain: band matvecs ----------------
        const int u = blockIdx.x - NB;
        const _Float16* Bu = Bd + (size_t)u * QNODES * 201 * BROW;
        const int r = tid;

        if (r < 232) { ab[0][r] = NEGV; ab[1][r] = NEGV; }
        float dv[BROW];
        if (r < 201) {
            #pragma unroll
            for (int k = 0; k < BROW; ++k) dv[k] = (float)Bu[r * BROW + k];
        }
        __syncthreads();
        if (r == 0) ab[0][QDRX] = 0.0f;    // alpha[0] = 0 (log2), offset QDRX
        __syncthreads();

        int cur = 0;
        for (int nd = 0; nd < QNODES; ++nd) {
            _Float16 nx[BROW];
            if (nd + 1 < QNODES && r < 201) {
                const _Float16* src = Bu + ((size_t)(nd + 1) * 201 + r) * BROW;
                #pragma unroll
                for (int k = 0; k < BROW; ++k) nx[k] = src[k];
            }
            float anew = NEGV;
            if (r < 201) {
                float tr[BROW];
                #pragma unroll
                for (int k = 0; k < BROW; ++k)
                    tr[k] = dv[k] + ab[cur][QDRX + r - k];
                float m = tr[0];
                #pragma unroll
                for (int k = 1; k < BROW; ++k) m = fmaxf(m, tr[k]);
                float s = 0.0f;
                #pragma unroll
                for (int k = 0; k < BROW; ++k)
                    s += __builtin_amdgcn_exp2f(tr[k] - m);
                anew = m + __builtin_amdgcn_logf(s);
            }
            if (r < 201) ab[cur ^ 1][QDRX + r] = anew;
            cur ^= 1;
            __syncthreads();
            if (r < 201) {
                #pragma unroll
                for (int k = 0; k < BROW; ++k) dv[k] = (float)nx[k];
            }
        }
        if (r == 0) dsc[NB + u] = ab[cur][QDRX + num_lens[u]] * LN2F;
    }
}

// ======================= Finalize ============================================
__global__ void mmi_finalize(const float* __restrict__ sc,
                             const int* __restrict__ sup,
                             float* __restrict__ out)
{
    const int tid = threadIdx.x;
    float tot_score = 0.0f, tot_frames = 0.0f, all_frames = 0.0f;
    if (tid < NB) {
        const float tot = sc[NB + tid] - sc[tid];
        const int nf = sup[tid * 3 + 2];
        const bool fin = isfinite(tot) && (tot > 0.5f * NEGV);
        tot_score  = fin ? tot : 0.0f;
        tot_frames = fin ? (float)nf : 0.0f;
        all_frames = (float)nf;
    }
    #pragma unroll
    for (int off = 32; off >= 1; off >>= 1) {
        tot_score  += __shfl_xor(tot_score, off, 64);
        tot_frames += __shfl_xor(tot_frames, off, 64);
        all_frames += __shfl_xor(all_frames, off, 64);
    }
    if (tid == 0) {
        out[0] = tot_score;
        out[1] = tot_frames;
        out[2] = all_frames;
    }
}

// ======================= Fallback (validated round-4 kernel) =================
#define XBF (16 * FF)
__global__ __launch_bounds__(256) void mmi_forward_fb(
    const float* __restrict__ x, const int* __restrict__ sup,
    const float* __restrict__ trans, const int* __restrict__ den_labels,
    const int* __restrict__ num_labels, const int* __restrict__ num_lens,
    float* __restrict__ ws)
{
    const int tid = threadIdx.x;
    if (blockIdx.x < NB) {
        __shared__ float sh_v[SS];
        __shared__ float sh_part[8 * SS];
        __shared__ float sh_red[4];
        __shared__ __align__(16) float xbuf[2][XBF];
        const int n = blockIdx.x, nf = sup[n * 3 + 2];
        const int g = tid & 31, c = tid >> 5;
        float4 e[16];
        #pragma unroll
        for (int j = 0; j < 16; ++j) {
            const float4 t4 = *(const float4*)(trans + (size_t)(16 * c + j) * SS + 4 * g);
            e[j] = make_float4(__expf(t4.x), __expf(t4.y), __expf(t4.z), __expf(t4.w));
        }
        const int lab = (tid < SS) ? den_labels[tid & (SS - 1)] : 0;
        const float* xb = x + (size_t)n * TT * FF;
        {
            const float4* s0 = (const float4*)xb;
            float4 p0 = s0[tid]; float4 p1; if (tid < 104) p1 = s0[256 + tid];
            float4* d0 = (float4*)xbuf[0];
            d0[tid] = p0; if (tid < 104) d0[256 + tid] = p1;
        }
        if (tid < SS) sh_v[tid] = (tid == 0) ? 1.0f : 0.0f;
        float logM = 0.0f, v = 0.0f, pe = 0.0f;
        float4 pf0, pf1;
        __syncthreads();
        for (int t = 0; t < nf; ++t) {
            const int b = t >> 4;
            if (tid < SS) pe = __expf(xbuf[b & 1][(t & 15) * FF + lab]);
            float4 aa[4];
            { const float4* av = (const float4*)(sh_v + 16 * c);
              aa[0] = av[0]; aa[1] = av[1]; aa[2] = av[2]; aa[3] = av[3]; }
            const float* as = (const float*)aa;
            float4 acc = make_float4(0.f, 0.f, 0.f, 0.f);
            #pragma unroll
            for (int j = 0; j < 16; ++j) {
                acc.x = fmaf(as[j], e[j].x, acc.x); acc.y = fmaf(as[j], e[j].y, acc.y);
                acc.z = fmaf(as[j], e[j].z, acc.z); acc.w = fmaf(as[j], e[j].w, acc.w);
            }
            *(float4*)(sh_part + c * SS + 4 * g) = acc;
            if ((t & 15) == 8) {
                const int tn = (b + 1) * 16;
                if (tn < nf) {
                    const float4* s = (const float4*)(xb + (size_t)tn * FF);
                    pf0 = s[tid]; if (tid < 104) pf1 = s[256 + tid];
                }
            }
            __syncthreads();
            const bool rs = ((t & 15) == 15);
            if (tid < SS) {
                float y = 0.0f;
                #pragma unroll
                for (int cc = 0; cc < 8; ++cc) y += sh_part[cc * SS + tid];
                v = y * pe;
                if (rs) {
                    float m = v;
                    #pragma unroll
                    for (int off = 32; off >= 1; off >>= 1)
                        m = fmaxf(m, __shfl_xor(m, off, 64));
                    if ((tid & 63) == 0) sh_red[tid >> 6] = m;
                }
            }
            if (rs) {
                const int tn = (b + 1) * 16;
                if (tn < nf) {
                    float4* dst = (float4*)xbuf[(b + 1) & 1];
                    dst[tid] = pf0; if (tid < 104) dst[256 + tid] = pf1;
                }
                __syncthreads();
                if (tid < SS) {
                    float mm = fmaxf(fmaxf(sh_red[0], sh_red[1]), 1e-37f);
                    v *= (1.0f / mm); logM += __logf(mm);
                }
            }
            if (tid < SS) sh_v[tid] = v;
            __syncthreads();
        }
        if (tid < SS) {
            float ssum = v;
            #pragma unroll
            for (int off = 32; off >= 1; off >>= 1) ssum += __shfl_xor(ssum, off, 64);
            if ((tid & 63) == 0) sh_red[2 + (tid >> 6)] = ssum;
        }
        __syncthreads();
        if (tid == 0) ws[n] = logM + __logf(sh_red[2] + sh_red[3]);
    } else {
        const int w = tid >> 6, l = tid & 63;
        const int n = (blockIdx.x - NB) * 4 + w;
        const int nf = sup[n * 3 + 2];
        const float* xb = x + (size_t)n * TT * FF;
        const int* nl = num_labels + n * LL;
        int li[4];
        #pragma unroll
        for (int k = 0; k < 4; ++k) li[k] = nl[min(4 * l + k, LL - 1)];
        float a4[4] = {NEGV, NEGV, NEGV, NEGV};
        float ea[4], eb[4];
        #pragma unroll
        for (int k = 0; k < 4; ++k) ea[k] = xb[li[k]];
        { const float* xr = xb + (size_t)min(1, nf - 1) * FF;
          #pragma unroll
          for (int k = 0; k < 4; ++k) eb[k] = xr[li[k]]; }
        auto step = [&](float (&ee)[4], int t) {
            float left = __shfl_up(a4[3], 1, 64);
            if (l == 0) left = (t == 0) ? 0.0f : NEGV;
            float prev = left;
            #pragma unroll
            for (int k = 0; k < 4; ++k) {
                const float a = a4[k], b = prev;
                const float mx = fmaxf(a, b), mn = fminf(a, b);
                const float nv = mx + __logf(1.0f + __expf(mn - mx)) + ee[k];
                prev = a4[k]; a4[k] = nv;
            }
            const int t2 = min(t + 2, nf - 1);
            const float* xr = xb + (size_t)t2 * FF;
            #pragma unroll
            for (int k = 0; k < 4; ++k) ee[k] = xr[li[k]];
        };
        int t = 0;
        while (t < nf) { step(ea, t); ++t; if (t >= nf) break; step(eb, t); ++t; }
        const int idx = num_lens[n] - 1;
        if ((idx >> 2) == l) {
            const int kk = idx & 3;
            float vv = (kk == 0) ? a4[0] : (kk == 1) ? a4[1] : (kk == 2) ? a4[2] : a4[3];
            ws[NB + n] = vv;
        }
    }
}

extern "C" void kernel_launch(void* const* d_in, const int* in_sizes, int n_in,
                              void* d_out, int out_size, void* d_ws, size_t ws_size,
                              hipStream_t stream) {
    const float* x          = (const float*)d_in[0];
    const int*   sup        = (const int*)d_in[1];
    const float* trans      = (const float*)d_in[2];
    const int*   den_labels = (const int*)d_in[3];
    const int*   num_labels = (const int*)d_in[4];
    const int*   num_lens   = (const int*)d_in[5];
    float* out = (float*)d_out;

    const size_t PBYTES = (size_t)NB * DNODES * 32768;              // 8,388,608
    const size_t BBYTES = (size_t)NB * QNODES * 201 * BROW * 2;     // 5,351,424
    const size_t SOFF   = PBYTES + BBYTES;
    const size_t NEEDED = SOFF + (NB * DNODES + 64) * sizeof(float);

    if (ws_size >= NEEDED) {
        unsigned*  Pout   = (unsigned*)d_ws;
        _Float16*  Bd     = (_Float16*)((char*)d_ws + PBYTES);
        float*     scales = (float*)((char*)d_ws + SOFF);
        float*     scores = scales + NB * DNODES;   // [0..15] den, [16..31] num
        mmi_nodes<<<dim3(512), dim3(512), 0, stream>>>(
            x, sup, trans, den_labels, num_labels, Pout, scales, Bd);
        mmi_chain<<<dim3(2 * NB), dim3(256), 0, stream>>>(
            (const unsigned short*)d_ws, Bd, scales, num_lens, scores);
        mmi_finalize<<<dim3(1), dim3(64), 0, stream>>>(scores, sup, out);
    } else {
        float* ws = (float*)d_ws;
        mmi_forward_fb<<<dim3(20), dim3(256), 0, stream>>>(
            x, sup, trans, den_labels, num_labels, num_lens, ws);
        mmi_finalize<<<dim3(1), dim3(64), 0, stream>>>(ws, sup, out);
    }
}